// Round 7
// baseline (38.050 us; speedup 1.0000x reference)
//
#include <hip/hip_runtime.h>

#define FD 32          // feature dim
#define RPB 16         // rows per block (A tile in LDS = RPB*128B = 2KB)
#define CPT 4          // cols per thread -> block covers 1024 cols
#define BLK 256        // threads per block

// packed dual-fp32 add: vb holds (-b0,-b1), va holds (a0,a1) -> (a-b) for 2 d's, 1 inst
__device__ __forceinline__ float2 pk_add(float2 vb, float2 va) {
    float2 r;
    asm("v_pk_add_f32 %0, %1, %2" : "=v"(r) : "v"(vb), "v"(va));
    return r;
}
// acc = max(acc, |x|, |y|) in ONE inst (abs = free VOP3 input modifier)
__device__ __forceinline__ float max3abs(float a, float x, float y) {
    float r;
    asm("v_max3_f32 %0, %1, abs(%2), abs(%3)" : "=v"(r) : "v"(a), "v"(x), "v"(y));
    return r;
}

// (256, 2): allow up to ~256 VGPR so the 128-VGPR B working set stays resident
// (round-4 pathology: default heuristics capped at 84 and silently re-loaded B;
//  round-5 pathology: (256,8) capped at 32 and spilled to scratch).
__global__ __launch_bounds__(256, 2) void cheb_kernel(
    const float* __restrict__ A, const float* __restrict__ B,
    float* __restrict__ C, int M)
{
    __shared__ float sA[RPB * FD];   // 2KB, linear, read via same-address broadcast

    const int tid = threadIdx.x;
    const int c0  = blockIdx.x * (BLK * CPT) + tid * CPT;  // this thread's 4 cols
    const int r0  = blockIdx.y * RPB;

    // ---- Stage A tile: 512 floats = 128 float4, threads 0..127, coalesced.
    if (tid < (RPB * FD) / 4) {
        *reinterpret_cast<float4*>(sA + tid * 4) =
            *reinterpret_cast<const float4*>(A + (size_t)r0 * FD + tid * 4);
    }

    // ---- This thread's 4 B columns, negated, in 4 separate 16-float2 arrays
    // (static indexing only -> register-resident, 128 VGPRs).
    float2 nb0[8], nb1[8], nb2[8], nb3[8];   // low half d=0..15
    float2 mb0[8], mb1[8], mb2[8], mb3[8];   // high half d=16..31
    {
        const float* brow = B + (size_t)c0 * FD;
#pragma unroll
        for (int q = 0; q < 4; ++q) {
            const float4 v0 = *reinterpret_cast<const float4*>(brow + q * 4);
            nb0[2 * q + 0] = make_float2(-v0.x, -v0.y);
            nb0[2 * q + 1] = make_float2(-v0.z, -v0.w);
            const float4 w0 = *reinterpret_cast<const float4*>(brow + 16 + q * 4);
            mb0[2 * q + 0] = make_float2(-w0.x, -w0.y);
            mb0[2 * q + 1] = make_float2(-w0.z, -w0.w);
            const float4 v1 = *reinterpret_cast<const float4*>(brow + FD + q * 4);
            nb1[2 * q + 0] = make_float2(-v1.x, -v1.y);
            nb1[2 * q + 1] = make_float2(-v1.z, -v1.w);
            const float4 w1 = *reinterpret_cast<const float4*>(brow + FD + 16 + q * 4);
            mb1[2 * q + 0] = make_float2(-w1.x, -w1.y);
            mb1[2 * q + 1] = make_float2(-w1.z, -w1.w);
            const float4 v2 = *reinterpret_cast<const float4*>(brow + 2 * FD + q * 4);
            nb2[2 * q + 0] = make_float2(-v2.x, -v2.y);
            nb2[2 * q + 1] = make_float2(-v2.z, -v2.w);
            const float4 w2 = *reinterpret_cast<const float4*>(brow + 2 * FD + 16 + q * 4);
            mb2[2 * q + 0] = make_float2(-w2.x, -w2.y);
            mb2[2 * q + 1] = make_float2(-w2.z, -w2.w);
            const float4 v3 = *reinterpret_cast<const float4*>(brow + 3 * FD + q * 4);
            nb3[2 * q + 0] = make_float2(-v3.x, -v3.y);
            nb3[2 * q + 1] = make_float2(-v3.z, -v3.w);
            const float4 w3 = *reinterpret_cast<const float4*>(brow + 3 * FD + 16 + q * 4);
            mb3[2 * q + 0] = make_float2(-w3.x, -w3.y);
            mb3[2 * q + 1] = make_float2(-w3.z, -w3.w);
        }
    }
    __syncthreads();

    // ---- Row loop: A comes from LDS via wave-uniform ds_read_b128 (broadcast,
    // conflict-free, ~120cyc latency hidden by 12+ waves/CU).
#pragma unroll 2
    for (int r = 0; r < RPB; ++r) {
        const float* arow = sA + r * FD;
        float acc0 = 0.0f, acc1 = 0.0f, acc2 = 0.0f, acc3 = 0.0f;
#pragma unroll
        for (int q = 0; q < 4; ++q) {
            const float4 av = *reinterpret_cast<const float4*>(arow + q * 4);       // d 4q..4q+3
            const float4 aw = *reinterpret_cast<const float4*>(arow + 16 + q * 4);  // d 16+4q..
            const float2 a01 = make_float2(av.x, av.y);
            const float2 a23 = make_float2(av.z, av.w);
            const float2 b01 = make_float2(aw.x, aw.y);
            const float2 b23 = make_float2(aw.z, aw.w);
            float2 d;
            d = pk_add(nb0[2 * q + 0], a01); acc0 = max3abs(acc0, d.x, d.y);
            d = pk_add(nb1[2 * q + 0], a01); acc1 = max3abs(acc1, d.x, d.y);
            d = pk_add(nb2[2 * q + 0], a01); acc2 = max3abs(acc2, d.x, d.y);
            d = pk_add(nb3[2 * q + 0], a01); acc3 = max3abs(acc3, d.x, d.y);
            d = pk_add(nb0[2 * q + 1], a23); acc0 = max3abs(acc0, d.x, d.y);
            d = pk_add(nb1[2 * q + 1], a23); acc1 = max3abs(acc1, d.x, d.y);
            d = pk_add(nb2[2 * q + 1], a23); acc2 = max3abs(acc2, d.x, d.y);
            d = pk_add(nb3[2 * q + 1], a23); acc3 = max3abs(acc3, d.x, d.y);
            d = pk_add(mb0[2 * q + 0], b01); acc0 = max3abs(acc0, d.x, d.y);
            d = pk_add(mb1[2 * q + 0], b01); acc1 = max3abs(acc1, d.x, d.y);
            d = pk_add(mb2[2 * q + 0], b01); acc2 = max3abs(acc2, d.x, d.y);
            d = pk_add(mb3[2 * q + 0], b01); acc3 = max3abs(acc3, d.x, d.y);
            d = pk_add(mb0[2 * q + 1], b23); acc0 = max3abs(acc0, d.x, d.y);
            d = pk_add(mb1[2 * q + 1], b23); acc1 = max3abs(acc1, d.x, d.y);
            d = pk_add(mb2[2 * q + 1], b23); acc2 = max3abs(acc2, d.x, d.y);
            d = pk_add(mb3[2 * q + 1], b23); acc3 = max3abs(acc3, d.x, d.y);
        }
        // coalesced: wave writes 1KB contiguous
        float4 o; o.x = acc0; o.y = acc1; o.z = acc2; o.w = acc3;
        *reinterpret_cast<float4*>(C + (size_t)(r0 + r) * M + c0) = o;
    }
}

extern "C" void kernel_launch(void* const* d_in, const int* in_sizes, int n_in,
                              void* d_out, int out_size, void* d_ws, size_t ws_size,
                              hipStream_t stream) {
    const float* A = (const float*)d_in[0];
    const float* B = (const float*)d_in[1];
    float* C = (float*)d_out;
    const int N = in_sizes[0] / FD;   // 4096
    const int M = in_sizes[1] / FD;   // 4096
    dim3 grid(M / (BLK * CPT), N / RPB);   // 4 x 256 = 1024 blocks; x-fastest ->
                                           // consecutive blocks share the same A tile
    cheb_kernel<<<grid, BLK, 0, stream>>>(A, B, C, M);
}